// Round 5
// baseline (148.323 us; speedup 1.0000x reference)
//
#include <hip/hip_runtime.h>
#include <stdint.h>

// HashedInterpolator R4: R3 pipeline + MLP boost in the two gather kernels.
// K4: 4 points/thread -> 32 independent L2 gathers in flight per wave.
// K5: 4 points/thread -> 4 gathers + contiguous 64B stores per thread.

#define HASH_MASK 0x3FFFFFu
#define P1 19349663u
#define P2 83492791u
#define NBUCK 64
#define PPT 16                    // points per thread in K1/K3
#define K3_BLOCK 256
#define PPB (K3_BLOCK * PPT)      // 4096 points per block

__device__ __forceinline__ uint32_t bucket_of(float px, float py, float pz) {
    uint32_t bx = ((uint32_t)(int)floorf(px * 128.0f)) >> 5;  // 0..3
    uint32_t by = ((uint32_t)(int)floorf(py * 128.0f)) >> 5;
    uint32_t bz = ((uint32_t)(int)floorf(pz * 128.0f)) >> 5;
    return (bx << 4) | (by << 2) | bz;
}

// ---- K1: per-block LDS histogram -> 64 global atomics per block ----
__global__ __launch_bounds__(K3_BLOCK) void hist_kernel(
    const float* __restrict__ pos, uint32_t* __restrict__ hist, int batch)
{
    __shared__ uint32_t h[NBUCK];
    int tid = threadIdx.x;
    size_t start = (size_t)blockIdx.x * PPB;
    if (tid < NBUCK) h[tid] = 0;
    __syncthreads();
#pragma unroll
    for (int k = 0; k < PPT; ++k) {
        size_t i = start + (size_t)k * K3_BLOCK + tid;
        if (i < (size_t)batch) {
            float px = pos[3 * i + 0];
            float py = pos[3 * i + 1];
            float pz = pos[3 * i + 2];
            atomicAdd(&h[bucket_of(px, py, pz)], 1u);
        }
    }
    __syncthreads();
    if (tid < NBUCK && h[tid]) atomicAdd(&hist[tid], h[tid]);
}

// ---- K2: 64-bin exclusive scan (one wave) ----
__global__ __launch_bounds__(64) void scan_kernel(
    const uint32_t* __restrict__ hist, uint32_t* __restrict__ cursor)
{
    int t = threadIdx.x;
    uint32_t v = hist[t];
    uint32_t inc = v;
    for (int off = 1; off < 64; off <<= 1) {
        uint32_t n = __shfl_up(inc, off);
        if (t >= off) inc += n;
    }
    cursor[t] = inc - v;   // exclusive
}

// ---- K3: LDS-staged scatter, coalesced global writes, emits inv perm ----
__global__ __launch_bounds__(K3_BLOCK) void scatter_kernel(
    const float* __restrict__ pos, uint32_t* __restrict__ cursor,
    float4* __restrict__ sorted, uint32_t* __restrict__ inv, int batch)
{
    __shared__ float4 staged[PPB];          // 64 KB
    __shared__ uint32_t h[NBUCK], lbase[NBUCK], gbase[NBUCK], lcur[NBUCK];
    int tid = threadIdx.x;
    size_t start = (size_t)blockIdx.x * PPB;

    if (tid < NBUCK) h[tid] = 0;
    __syncthreads();

    float px[PPT], py[PPT], pz[PPT];
    uint32_t bb[PPT];
#pragma unroll
    for (int k = 0; k < PPT; ++k) {
        size_t i = start + (size_t)k * K3_BLOCK + tid;
        px[k] = pos[3 * i + 0];
        py[k] = pos[3 * i + 1];
        pz[k] = pos[3 * i + 2];
        bb[k] = bucket_of(px[k], py[k], pz[k]);
        atomicAdd(&h[bb[k]], 1u);
    }
    __syncthreads();

    if (tid < NBUCK) {
        uint32_t v = h[tid];
        uint32_t inc = v;
        for (int off = 1; off < 64; off <<= 1) {
            uint32_t n = __shfl_up(inc, off);
            if (tid >= off) inc += n;
        }
        uint32_t excl = inc - v;
        lbase[tid] = excl;
        lcur[tid] = excl;
        gbase[tid] = atomicAdd(&cursor[tid], v);
    }
    __syncthreads();

#pragma unroll
    for (int k = 0; k < PPT; ++k) {
        size_t i = start + (size_t)k * K3_BLOCK + tid;
        uint32_t slot = atomicAdd(&lcur[bb[k]], 1u);
        staged[slot] = make_float4(px[k], py[k], pz[k], __uint_as_float((uint32_t)i));
        inv[i] = gbase[bb[k]] + (slot - lbase[bb[k]]);   // coalesced 4B write
    }
    __syncthreads();

#pragma unroll
    for (int k = 0; k < PPT; ++k) {
        int j = k * K3_BLOCK + tid;
        float4 s = staged[j];
        uint32_t b = bucket_of(s.x, s.y, s.z);
        sorted[gbase[b] + ((uint32_t)j - lbase[b])] = s;
    }
}

// ---- K4: interpolate 4 sorted points/thread, results in place ----
__global__ __launch_bounds__(256) void interp_sorted4_kernel(
    float4* __restrict__ sorted, const float* __restrict__ table,
    int nthreads, int nwg)
{
    int bid = blockIdx.x;
    int q = nwg >> 3;                  // nwg divisible by 8
    int swz = (bid & 7) * q + (bid >> 3);
    int t = swz * 256 + threadIdx.x;
    if (t >= nthreads) return;

    float4 s[4];
#pragma unroll
    for (int p = 0; p < 4; ++p) s[p] = sorted[4 * (size_t)t + p];

    const float inv = 1.0f / 128.0f;  // exact

    float w0x[4], w1x[4], w0y[4], w1y[4], w0z[4], w1z[4];
    uint32_t hx0[4], hx1[4], hy0[4], hy1[4], hz0[4], hz1[4];
#pragma unroll
    for (int p = 0; p < 4; ++p) {
        float px = s[p].x, py = s[p].y, pz = s[p].z;
        int lx = (int)floorf(px * 128.0f);
        int ly = (int)floorf(py * 128.0f);
        int lz = (int)floorf(pz * 128.0f);
        w0x[p] = (px - (float)lx * inv) * 128.0f;
        w1x[p] = ((float)(lx + 1) * inv - px) * 128.0f;
        w0y[p] = (py - (float)ly * inv) * 128.0f;
        w1y[p] = ((float)(ly + 1) * inv - py) * 128.0f;
        w0z[p] = (pz - (float)lz * inv) * 128.0f;
        w1z[p] = ((float)(lz + 1) * inv - pz) * 128.0f;
        hx0[p] = (uint32_t)lx;
        hx1[p] = (uint32_t)(lx + 1);
        hy0[p] = (uint32_t)ly * P1;
        hy1[p] = (uint32_t)(ly + 1) * P1;
        hz0[p] = (uint32_t)lz * P2;
        hz1[p] = (uint32_t)(lz + 1) * P2;
    }

    float4 r[4];
#pragma unroll
    for (int p = 0; p < 4; ++p) {
        float acc0 = 0.f, acc1 = 0.f, acc2 = 0.f, acc3 = 0.f;
#pragma unroll
        for (int c = 0; c < 8; ++c) {
            int bx = (c >> 2) & 1;
            int by = (c >> 1) & 1;
            int bz = c & 1;
            uint32_t hh = ((bx ? hx1[p] : hx0[p]) ^ (by ? hy1[p] : hy0[p]) ^
                           (bz ? hz1[p] : hz0[p])) & HASH_MASK;
            const float4 v = *reinterpret_cast<const float4*>(table + (size_t)hh * 4);
            float w = ((bx ? w1x[p] : w0x[p]) * (by ? w1y[p] : w0y[p])) *
                      (bz ? w1z[p] : w0z[p]);
            acc0 += v.x * w;
            acc1 += v.y * w;
            acc2 += v.z * w;
            acc3 += v.w * w;
        }
        r[p] = make_float4(acc0, acc1, acc2, acc3);
    }

#pragma unroll
    for (int p = 0; p < 4; ++p) sorted[4 * (size_t)t + p] = r[p];
}

// ---- K5: un-permute via gather, 4 points/thread ----
__global__ __launch_bounds__(256) void unpermute4_kernel(
    const float4* __restrict__ sorted, const uint4* __restrict__ inv4,
    float4* __restrict__ out4, int nthreads)
{
    int t = blockIdx.x * 256 + threadIdx.x;
    if (t >= nthreads) return;
    uint4 iv = inv4[t];
    float4 a = sorted[iv.x];
    float4 b = sorted[iv.y];
    float4 c = sorted[iv.z];
    float4 d = sorted[iv.w];
    out4[4 * (size_t)t + 0] = a;
    out4[4 * (size_t)t + 1] = b;
    out4[4 * (size_t)t + 2] = c;
    out4[4 * (size_t)t + 3] = d;
}

// ---- fallback: direct (R0) ----
__global__ __launch_bounds__(256) void interp_direct_kernel(
    const float* __restrict__ pos, const float* __restrict__ table,
    float4* __restrict__ out4, int batch)
{
    int i = blockIdx.x * 256 + threadIdx.x;
    if (i >= batch) return;
    float px = pos[3 * (size_t)i + 0];
    float py = pos[3 * (size_t)i + 1];
    float pz = pos[3 * (size_t)i + 2];

    int lx = (int)floorf(px * 128.0f);
    int ly = (int)floorf(py * 128.0f);
    int lz = (int)floorf(pz * 128.0f);
    const float inv = 1.0f / 128.0f;
    float w0x = (px - (float)lx * inv) * 128.0f;
    float w1x = ((float)(lx + 1) * inv - px) * 128.0f;
    float w0y = (py - (float)ly * inv) * 128.0f;
    float w1y = ((float)(ly + 1) * inv - py) * 128.0f;
    float w0z = (pz - (float)lz * inv) * 128.0f;
    float w1z = ((float)(lz + 1) * inv - pz) * 128.0f;
    uint32_t hx0 = (uint32_t)lx, hx1 = (uint32_t)(lx + 1);
    uint32_t hy0 = (uint32_t)ly * P1, hy1 = (uint32_t)(ly + 1) * P1;
    uint32_t hz0 = (uint32_t)lz * P2, hz1 = (uint32_t)(lz + 1) * P2;
    float acc0 = 0.f, acc1 = 0.f, acc2 = 0.f, acc3 = 0.f;
#pragma unroll
    for (int c = 0; c < 8; ++c) {
        int bx = (c >> 2) & 1, by = (c >> 1) & 1, bz = c & 1;
        uint32_t h = ((bx ? hx1 : hx0) ^ (by ? hy1 : hy0) ^ (bz ? hz1 : hz0)) & HASH_MASK;
        const float4 v = *reinterpret_cast<const float4*>(table + (size_t)h * 4);
        float w = ((bx ? w1x : w0x) * (by ? w1y : w0y)) * (bz ? w1z : w0z);
        acc0 += v.x * w; acc1 += v.y * w; acc2 += v.z * w; acc3 += v.w * w;
    }
    out4[i] = make_float4(acc0, acc1, acc2, acc3);
}

extern "C" void kernel_launch(void* const* d_in, const int* in_sizes, int n_in,
                              void* d_out, int out_size, void* d_ws, size_t ws_size,
                              hipStream_t stream) {
    const float* pos   = (const float*)d_in[0];   // (2^21, 3)
    const float* table = (const float*)d_in[1];   // (2^22, 4)
    float4* out4 = (float4*)d_out;                // (2^21, 4)

    int batch = in_sizes[0] / 3;                  // 2^21
    int blocks256 = (batch + 255) / 256;          // 8192

    size_t sorted_off = 512;
    size_t inv_off = sorted_off + (size_t)batch * 16;
    size_t need = inv_off + (size_t)batch * 4;

    int nthreads4 = batch / 4;                    // 524288
    int blocks4 = nthreads4 / 256;                // 2048

    bool exact = (batch % PPB == 0) && (batch % 1024 == 0) && ((blocks4 & 7) == 0);
    if (ws_size < need || !exact) {
        interp_direct_kernel<<<blocks256, 256, 0, stream>>>(pos, table, out4, batch);
        return;
    }

    uint32_t* hist   = (uint32_t*)d_ws;                        // 256 B
    uint32_t* cursor = (uint32_t*)((char*)d_ws + 256);         // 256 B
    float4*   sorted = (float4*)((char*)d_ws + sorted_off);    // 32 MB
    uint32_t* inv    = (uint32_t*)((char*)d_ws + inv_off);     // 8 MB

    int sblocks = batch / PPB;                                 // 512

    hipMemsetAsync(hist, 0, NBUCK * sizeof(uint32_t), stream);
    hist_kernel<<<sblocks, K3_BLOCK, 0, stream>>>(pos, hist, batch);
    scan_kernel<<<1, 64, 0, stream>>>(hist, cursor);
    scatter_kernel<<<sblocks, K3_BLOCK, 0, stream>>>(pos, cursor, sorted, inv, batch);
    interp_sorted4_kernel<<<blocks4, 256, 0, stream>>>(sorted, table, nthreads4, blocks4);
    unpermute4_kernel<<<blocks4, 256, 0, stream>>>(sorted, (const uint4*)inv, out4, nthreads4);
}

// Round 6
// 124.424 us; speedup vs baseline: 1.1921x; 1.1921x over previous
//
#include <hip/hip_runtime.h>
#include <stdint.h>

// HashedInterpolator R5: R3 pipeline, K5 eliminated.
// K4 reads sorted points (coalesced), interpolates (1 pt/thread — R3's proven
// form), and scatters the result directly to out[orig] (orig carried in s.w).
// Drops: inv permutation (8 MB write + 8 MB read), K5's 2M-request gather and
// 32 MB coalesced write.

#define HASH_MASK 0x3FFFFFu
#define P1 19349663u
#define P2 83492791u
#define NBUCK 64
#define PPT 16                    // points per thread in K1/K3
#define K3_BLOCK 256
#define PPB (K3_BLOCK * PPT)      // 4096 points per block

__device__ __forceinline__ uint32_t bucket_of(float px, float py, float pz) {
    uint32_t bx = ((uint32_t)(int)floorf(px * 128.0f)) >> 5;  // 0..3
    uint32_t by = ((uint32_t)(int)floorf(py * 128.0f)) >> 5;
    uint32_t bz = ((uint32_t)(int)floorf(pz * 128.0f)) >> 5;
    return (bx << 4) | (by << 2) | bz;
}

__device__ __forceinline__ float4 interp_point(float px, float py, float pz,
                                               const float* __restrict__ table) {
    int lx = (int)floorf(px * 128.0f);
    int ly = (int)floorf(py * 128.0f);
    int lz = (int)floorf(pz * 128.0f);

    const float inv = 1.0f / 128.0f;  // exact
    float w0x = (px - (float)lx * inv) * 128.0f;
    float w1x = ((float)(lx + 1) * inv - px) * 128.0f;
    float w0y = (py - (float)ly * inv) * 128.0f;
    float w1y = ((float)(ly + 1) * inv - py) * 128.0f;
    float w0z = (pz - (float)lz * inv) * 128.0f;
    float w1z = ((float)(lz + 1) * inv - pz) * 128.0f;

    uint32_t hx0 = (uint32_t)lx;
    uint32_t hx1 = (uint32_t)(lx + 1);
    uint32_t hy0 = (uint32_t)ly * P1;
    uint32_t hy1 = (uint32_t)(ly + 1) * P1;
    uint32_t hz0 = (uint32_t)lz * P2;
    uint32_t hz1 = (uint32_t)(lz + 1) * P2;

    float acc0 = 0.f, acc1 = 0.f, acc2 = 0.f, acc3 = 0.f;
#pragma unroll
    for (int c = 0; c < 8; ++c) {
        int bx = (c >> 2) & 1;
        int by = (c >> 1) & 1;
        int bz = c & 1;
        uint32_t h = ((bx ? hx1 : hx0) ^ (by ? hy1 : hy0) ^ (bz ? hz1 : hz0)) & HASH_MASK;
        const float4 v = *reinterpret_cast<const float4*>(table + (size_t)h * 4);
        float w = ((bx ? w1x : w0x) * (by ? w1y : w0y)) * (bz ? w1z : w0z);
        acc0 += v.x * w;
        acc1 += v.y * w;
        acc2 += v.z * w;
        acc3 += v.w * w;
    }
    return make_float4(acc0, acc1, acc2, acc3);
}

// ---- K1: per-block LDS histogram -> 64 global atomics per block ----
__global__ __launch_bounds__(K3_BLOCK) void hist_kernel(
    const float* __restrict__ pos, uint32_t* __restrict__ hist, int batch)
{
    __shared__ uint32_t h[NBUCK];
    int tid = threadIdx.x;
    size_t start = (size_t)blockIdx.x * PPB;
    if (tid < NBUCK) h[tid] = 0;
    __syncthreads();
#pragma unroll
    for (int k = 0; k < PPT; ++k) {
        size_t i = start + (size_t)k * K3_BLOCK + tid;
        if (i < (size_t)batch) {
            float px = pos[3 * i + 0];
            float py = pos[3 * i + 1];
            float pz = pos[3 * i + 2];
            atomicAdd(&h[bucket_of(px, py, pz)], 1u);
        }
    }
    __syncthreads();
    if (tid < NBUCK && h[tid]) atomicAdd(&hist[tid], h[tid]);
}

// ---- K2: 64-bin exclusive scan (one wave) ----
__global__ __launch_bounds__(64) void scan_kernel(
    const uint32_t* __restrict__ hist, uint32_t* __restrict__ cursor)
{
    int t = threadIdx.x;
    uint32_t v = hist[t];
    uint32_t inc = v;
    for (int off = 1; off < 64; off <<= 1) {
        uint32_t n = __shfl_up(inc, off);
        if (t >= off) inc += n;
    }
    cursor[t] = inc - v;   // exclusive
}

// ---- K3: LDS-staged scatter, coalesced global writes ----
__global__ __launch_bounds__(K3_BLOCK) void scatter_kernel(
    const float* __restrict__ pos, uint32_t* __restrict__ cursor,
    float4* __restrict__ sorted, int batch)
{
    __shared__ float4 staged[PPB];          // 64 KB
    __shared__ uint32_t h[NBUCK], lbase[NBUCK], gbase[NBUCK], lcur[NBUCK];
    int tid = threadIdx.x;
    size_t start = (size_t)blockIdx.x * PPB;

    if (tid < NBUCK) h[tid] = 0;
    __syncthreads();

    float px[PPT], py[PPT], pz[PPT];
    uint32_t bb[PPT];
#pragma unroll
    for (int k = 0; k < PPT; ++k) {
        size_t i = start + (size_t)k * K3_BLOCK + tid;
        px[k] = pos[3 * i + 0];
        py[k] = pos[3 * i + 1];
        pz[k] = pos[3 * i + 2];
        bb[k] = bucket_of(px[k], py[k], pz[k]);
        atomicAdd(&h[bb[k]], 1u);
    }
    __syncthreads();

    if (tid < NBUCK) {
        uint32_t v = h[tid];
        uint32_t inc = v;
        for (int off = 1; off < 64; off <<= 1) {
            uint32_t n = __shfl_up(inc, off);
            if (tid >= off) inc += n;
        }
        uint32_t excl = inc - v;
        lbase[tid] = excl;
        lcur[tid] = excl;
        gbase[tid] = atomicAdd(&cursor[tid], v);
    }
    __syncthreads();

#pragma unroll
    for (int k = 0; k < PPT; ++k) {
        size_t i = start + (size_t)k * K3_BLOCK + tid;
        uint32_t slot = atomicAdd(&lcur[bb[k]], 1u);
        staged[slot] = make_float4(px[k], py[k], pz[k], __uint_as_float((uint32_t)i));
    }
    __syncthreads();

    // linear LDS -> global copy; consecutive slots in a bucket run are
    // consecutive global addresses -> coalesced
#pragma unroll
    for (int k = 0; k < PPT; ++k) {
        int j = k * K3_BLOCK + tid;
        float4 s = staged[j];
        uint32_t b = bucket_of(s.x, s.y, s.z);
        sorted[gbase[b] + ((uint32_t)j - lbase[b])] = s;
    }
}

// ---- K4: interpolate sorted points, scatter result to out[orig] ----
__global__ __launch_bounds__(256) void interp_scatter_kernel(
    const float4* __restrict__ sorted, const float* __restrict__ table,
    float4* __restrict__ out4, int batch, int nwg)
{
    // XCD-chunked bijective swizzle (nwg divisible by 8)
    int bid = blockIdx.x;
    int q = nwg >> 3;
    int swz = (bid & 7) * q + (bid >> 3);
    int i = swz * 256 + threadIdx.x;
    if (i >= batch) return;

    float4 s = sorted[i];
    float4 r = interp_point(s.x, s.y, s.z, table);
    uint32_t orig = __float_as_uint(s.w);
    out4[orig] = r;
}

// ---- fallback: direct (R0) ----
__global__ __launch_bounds__(256) void interp_direct_kernel(
    const float* __restrict__ pos, const float* __restrict__ table,
    float4* __restrict__ out4, int batch)
{
    int i = blockIdx.x * 256 + threadIdx.x;
    if (i >= batch) return;
    float px = pos[3 * (size_t)i + 0];
    float py = pos[3 * (size_t)i + 1];
    float pz = pos[3 * (size_t)i + 2];
    out4[i] = interp_point(px, py, pz, table);
}

extern "C" void kernel_launch(void* const* d_in, const int* in_sizes, int n_in,
                              void* d_out, int out_size, void* d_ws, size_t ws_size,
                              hipStream_t stream) {
    const float* pos   = (const float*)d_in[0];   // (2^21, 3)
    const float* table = (const float*)d_in[1];   // (2^22, 4)
    float4* out4 = (float4*)d_out;                // (2^21, 4)

    int batch = in_sizes[0] / 3;                  // 2^21
    int blocks256 = (batch + 255) / 256;          // 8192

    size_t sorted_off = 512;
    size_t need = sorted_off + (size_t)batch * 16;

    bool exact = (batch % PPB == 0) && ((blocks256 & 7) == 0);
    if (ws_size < need || !exact) {
        interp_direct_kernel<<<blocks256, 256, 0, stream>>>(pos, table, out4, batch);
        return;
    }

    uint32_t* hist   = (uint32_t*)d_ws;                        // 256 B
    uint32_t* cursor = (uint32_t*)((char*)d_ws + 256);         // 256 B
    float4*   sorted = (float4*)((char*)d_ws + sorted_off);    // 32 MB

    int sblocks = batch / PPB;                                 // 512

    hipMemsetAsync(hist, 0, NBUCK * sizeof(uint32_t), stream);
    hist_kernel<<<sblocks, K3_BLOCK, 0, stream>>>(pos, hist, batch);
    scan_kernel<<<1, 64, 0, stream>>>(hist, cursor);
    scatter_kernel<<<sblocks, K3_BLOCK, 0, stream>>>(pos, cursor, sorted, batch);
    interp_scatter_kernel<<<blocks256, 256, 0, stream>>>(sorted, table, out4, batch, blocks256);
}